// Round 8
// baseline (144.015 us; speedup 1.0000x reference)
//
#include <hip/hip_runtime.h>

#define B_ 4
#define N_ 4096
#define C_ 256
#define M_ 2048

typedef __attribute__((ext_vector_type(8))) short short8;
typedef __attribute__((ext_vector_type(4))) short short4v;
typedef __attribute__((ext_vector_type(4))) float f32x4;

union U16x8 { uint4 u4; unsigned short us[8]; short8 s8; };
union U16x4 { uint2 u2; unsigned short us[4]; short4v s4; };

__device__ __forceinline__ float bf2f(unsigned short h) {
    unsigned int u = ((unsigned int)h) << 16;
    return __builtin_bit_cast(float, u);
}
__device__ __forceinline__ unsigned short f2bf(float f) {
    unsigned int u = __builtin_bit_cast(unsigned int, f);
    u += 0x7FFFu + ((u >> 16) & 1u);
    return (unsigned short)(u >> 16);
}

#define GLB_AS(p) ((const __attribute__((address_space(1))) unsigned int*)(p))
#define LDS_AS(p) ((__attribute__((address_space(3))) unsigned int*)(p))

// 16x16x16 bf16 MFMA: builtin if available, else raw encoding via inline asm.
__device__ __forceinline__ f32x4 mfma16x16(short4v a, short4v b, f32x4 c) {
#if __has_builtin(__builtin_amdgcn_mfma_f32_16x16x16bf16_1k)
    return __builtin_amdgcn_mfma_f32_16x16x16bf16_1k(a, b, c, 0, 0, 0);
#else
    asm("v_mfma_f32_16x16x16_bf16 %0, %1, %2, %0" : "+v"(c) : "v"(a), "v"(b));
    return c;
#endif
}

// ---- Fused prepass (WIDE): norms + casts. grid (M/64, B), 1024 thr ----
__global__ __launch_bounds__(1024) void k_prep(const float* __restrict__ g,
                                               unsigned short* __restrict__ gcm,
                                               unsigned short* __restrict__ gmc) {
    __shared__ float red[16][64];
    __shared__ float sInv[64];
    __shared__ unsigned short T[64 * 66];   // normalized [c][m] tile, odd-dword stride
    const int b = blockIdx.y, m0 = blockIdx.x * 64;
    const int tid = threadIdx.x;                // 0..1023
    const int ml = tid & 63, cq = tid >> 6;     // cq in [0,16)

    // phase 1: norms — each thread sums 16 c-rows
    const float* gb = g + (size_t)b * C_ * M_ + m0 + ml;
    float ss = 0.f;
#pragma unroll 4
    for (int i = 0; i < 16; ++i) {
        float v = gb[(size_t)(cq * 16 + i) * M_];
        ss += v * v;
    }
    red[cq][ml] = ss;
    __syncthreads();
    if (cq == 0) {
        float t = 0.f;
#pragma unroll
        for (int k = 0; k < 16; ++k) t += red[k][ml];
        sInv[ml] = 1.f / fmaxf(sqrtf(t), 1e-8f);
    }
    __syncthreads();

    // phase 2: casts, 4 c-tiles of 64
    for (int c0 = 0; c0 < C_; c0 += 64) {
        const float* gbase = g + ((size_t)b * C_ + c0) * M_ + m0;
        unsigned short* gcmb = gcm + ((size_t)b * C_ + c0) * M_ + m0;
        {
            int id = tid;                       // 1024 float4-chunks, 1 per thread
            int ci = id >> 4, mq = (id & 15) * 4;
            float4 v = *(const float4*)(gbase + (size_t)ci * M_ + mq);
            uint2 pk;
            pk.x = (unsigned)f2bf(v.x) | ((unsigned)f2bf(v.y) << 16);
            pk.y = (unsigned)f2bf(v.z) | ((unsigned)f2bf(v.w) << 16);
            *(uint2*)(gcmb + (size_t)ci * M_ + mq) = pk;
            T[ci * 66 + mq + 0] = f2bf(v.x * sInv[mq + 0]);
            T[ci * 66 + mq + 1] = f2bf(v.y * sInv[mq + 1]);
            T[ci * 66 + mq + 2] = f2bf(v.z * sInv[mq + 2]);
            T[ci * 66 + mq + 3] = f2bf(v.w * sInv[mq + 3]);
        }
        __syncthreads();
        unsigned short* gmcb = gmc + ((size_t)b * M_ + m0) * C_ + c0;
        if (tid < 512) {                        // 512 8-short chunks
            int mr = tid >> 3, cc8 = (tid & 7) * 8;
            U16x8 t;
#pragma unroll
            for (int k = 0; k < 8; ++k) t.us[k] = T[(cc8 + k) * 66 + mr];
            *(uint4*)(gmcb + (size_t)mr * C_ + cc8) = t.u4;
        }
        __syncthreads();   // T reused next tile
    }
}

// ---------------- Main fused kernel (v14) ----------------
// v13/v10 compute structure (64 rows/block, 8 waves, key-split, P in regs)
// + DOUBLE-BUFFERED tiles, one __syncthreads per iter. v11/v12's failure was
// NOT the sync protocol: their dma lambdas were called with a TILE index where
// the lambda expected a KEY index (64x address error -> deterministic garbage,
// identical absmax under both sync schemes). v14's lambdas take the tile index
// and scale INTERNALLY (unit-safe by construction).
// Pipeline: iter t reads buf[t&1]; end-of-iter barrier proves readers done;
// dma(tile t+2 -> buf[t&1]) then issues with a full iteration to land, so the
// next barrier's vmcnt(0) drain waits on a ~2000-cyc-old load (~free).
__global__ __launch_bounds__(512, 1) void k_main(
    const float* __restrict__ l,
    const unsigned short* __restrict__ gcm,    // [B][C][M] raw bf16   (GEMM2 B, k=m contig)
    const unsigned short* __restrict__ gmc,    // [B][M][C] normalized (GEMM1 A, k=c contig)
    float* __restrict__ out)
{
    __shared__ __align__(16) char sMem[132096];
    unsigned short* sGmcD = (unsigned short*)sMem;             // ghat [2][64][256], 2x32 KB
    unsigned short* sGcmD = (unsigned short*)(sMem + 65536);   // graw [2][256][64], 2x32 KB
    float (*sDen)[64] = (float (*)[64])(sMem + 131072);        // [4 kh][64 rows]

    const int tid = threadIdx.x;
    const int w = tid >> 6;
    const int lane = tid & 63;
    const int l15 = lane & 15;
    const int quad = lane >> 4;
    const int kh = w & 3;        // key-quarter
    const int rh = w >> 2;       // row-half

    // ---- batch-clustered XCD swizzle (bijective over 256 blocks) ----
    const int bid = blockIdx.x;
    const int xcd = bid & 7;
    const int b = xcd >> 1;                                   // 2 XCDs per batch
    const int row0 = (((bid >> 3) << 1) | (xcd & 1)) * 64;    // 64-row tile in [0,4096)

    // per-lane DMA source offsets (shorts), XOR chunk swizzles match the read patterns
    int goffA[4], goffB[4];
#pragma unroll
    for (int i = 0; i < 4; ++i) {
        int p = (w * 4 + i) * 64 + lane;                   // p in [0,2048)
        int rA = p >> 5;                                   // row in [0,64), 32 granules/row
        goffA[i] = rA * 256 + (((p & 31) ^ (rA & 31)) << 3);
        int rB = p >> 3;                                   // row in [0,256), 8 granules/row
        goffB[i] = rB * 2048 + (((p & 7) ^ ((rB >> 1) & 7)) << 3);
    }

    const unsigned short* gmc_b = gmc + (size_t)b * M_ * C_;
    const unsigned short* gcm_b = gcm + (size_t)b * C_ * M_;

    // tile = 64-key tile index in [0,32). A-tile source stride: 64*256 shorts.
    // B-tile source stride: 64 shorts (keys contiguous along M).
    auto dmaA = [&](int tile, int buf) {
#pragma unroll
        for (int i = 0; i < 4; ++i)
            __builtin_amdgcn_global_load_lds(GLB_AS(gmc_b + (size_t)tile * 16384 + goffA[i]),
                                             LDS_AS(&sGmcD[buf * 16384 + (w * 4 + i) * 512]), 16, 0, 0);
    };
    auto dmaB = [&](int tile, int buf) {
#pragma unroll
        for (int i = 0; i < 4; ++i)
            __builtin_amdgcn_global_load_lds(GLB_AS(gcm_b + (size_t)tile * 64 + goffB[i]),
                                             LDS_AS(&sGcmD[buf * 16384 + (w * 4 + i) * 512]), 16, 0, 0);
    };

    // stage tiles 0 and 1; both drained at the pre-loop barrier
    dmaA(0, 0);
    dmaB(0, 0);
    dmaA(1, 1);
    dmaB(1, 1);

    // ---- Q: my 32 rows (row-half rh), row norm, normalize -> bf16 B-frags ----
    short8 qf[2][8];
#pragma unroll
    for (int rt = 0; rt < 2; ++rt) {
        const float* lrow = l + ((size_t)b * N_ + row0 + rh * 32 + rt * 16 + l15) * C_;
        U16x8 qt[8];
        float ss = 0.f;
#pragma unroll
        for (int kk = 0; kk < 8; ++kk) {
            float4 x0 = *(const float4*)(lrow + kk * 32 + quad * 8);
            float4 x1 = *(const float4*)(lrow + kk * 32 + quad * 8 + 4);
            ss += x0.x*x0.x + x0.y*x0.y + x0.z*x0.z + x0.w*x0.w;
            ss += x1.x*x1.x + x1.y*x1.y + x1.z*x1.z + x1.w*x1.w;
            qt[kk].us[0] = f2bf(x0.x); qt[kk].us[1] = f2bf(x0.y);
            qt[kk].us[2] = f2bf(x0.z); qt[kk].us[3] = f2bf(x0.w);
            qt[kk].us[4] = f2bf(x1.x); qt[kk].us[5] = f2bf(x1.y);
            qt[kk].us[6] = f2bf(x1.z); qt[kk].us[7] = f2bf(x1.w);
        }
        ss += __shfl_xor(ss, 16);
        ss += __shfl_xor(ss, 32);
        const float invl = 1.0f / fmaxf(sqrtf(ss), 1e-8f);
#pragma unroll
        for (int kk = 0; kk < 8; ++kk) {
            U16x8 t;
#pragma unroll
            for (int j = 0; j < 8; ++j) t.us[j] = f2bf(bf2f(qt[kk].us[j]) * invl);
            qf[rt][kk] = t.s8;
        }
    }

    __syncthreads();   // drains DMA tiles 0+1 (and Q loads); tile 0 ready

    f32x4 zero = {0.f, 0.f, 0.f, 0.f};
    f32x4 o[2][16];    // per-wave PARTIAL O (its 16 keys): [row-tile][c-tile 16c]
#pragma unroll
    for (int i = 0; i < 2; ++i)
#pragma unroll
        for (int j = 0; j < 16; ++j) o[i][j] = zero;
    float dl0 = 0.f, dl1 = 0.f;

    // GEMM1 A-frag source: my 16 key-rows; GEMM2 B-frag source: chunk-XOR swizzled
    const unsigned short* gAbase = &sGmcD[(kh * 16 + l15) * 256];
    const int rxor = (kh * 16 + l15) & 31;
    const int chunkXor = (kh * 4 + quad) ^ (l15 & 14);
    const unsigned short* gBbase = &sGcmD[l15 * 64 + (chunkXor << 2)];

    for (int mt = 0; mt < 32; ++mt) {
        const int cur = mt & 1;
        const unsigned short* gA = gAbase + cur * 16384;
        const unsigned short* gB = gBbase + cur * 16384;

        // GEMM1 (swapped): S^T[16 keys][16 rows] per row-tile, K=256
        f32x4 sa0 = zero, sa1 = zero;
#pragma unroll
        for (int kk = 0; kk < 8; ++kk) {
            short8 ag = *(const short8*)&gA[((kk * 4 + quad) ^ rxor) << 3];
            sa0 = __builtin_amdgcn_mfma_f32_16x16x32_bf16(ag, qf[0][kk], sa0, 0, 0, 0);
            sa1 = __builtin_amdgcn_mfma_f32_16x16x32_bf16(ag, qf[1][kk], sa1, 0, 0, 0);
        }
        // p = exp(cos/tau); lane holds (q-row = l15, key = quad*4+r) -> already
        // the 16x16x16 A-frag layout. Accumulate denominator partials.
        U16x4 pk0, pk1;
#pragma unroll
        for (int r = 0; r < 4; ++r) {
            float p0 = exp2f(sa0[r] * 3.6067376022224085f);
            float p1 = exp2f(sa1[r] * 3.6067376022224085f);
            dl0 += p0; dl1 += p1;
            pk0.us[r] = f2bf(p0);
            pk1.us[r] = f2bf(p1);
        }

        // GEMM2 key-split: O_partial[32 rows][256 c] += P[32][16 keys] * V[16][256]
#pragma unroll
        for (int ct = 0; ct < 16; ++ct) {
            short4v bb = *(const short4v*)&gB[ct * 1024];
            o[0][ct] = mfma16x16(pk0.s4, bb, o[0][ct]);
            o[1][ct] = mfma16x16(pk1.s4, bb, o[1][ct]);
        }

        // one barrier per iter: all reads of buf[cur] retired; also drains
        // dma(tile mt+1) issued a full iteration ago (wait ~free). Refill buf[cur].
        __syncthreads();
        if (mt < 30) {
            dmaA(mt + 2, cur);
            dmaB(mt + 2, cur);
        }
    }

    // ---- denominators: quad-reduce, publish per key-quarter per row ----
    {
        float d0 = dl0;
        d0 += __shfl_xor(d0, 16);
        d0 += __shfl_xor(d0, 32);
        float d1 = dl1;
        d1 += __shfl_xor(d1, 16);
        d1 += __shfl_xor(d1, 32);
        if (quad == 0) {
            sDen[kh][rh * 32 + l15] = d0;
            sDen[kh][rh * 32 + 16 + l15] = d1;
        }
    }

    // ---- O reduction: 4 static rounds (rh x rt) through 64 KB LDS dump ----
    // slot(kh', j, quad, l15) = kh'*1024 + j*64 + quad*16 + l15  (f32x4 units)
    // All indices static (rule #20). red4 covers sMem[0,65536); sDen at 131072
    // does not alias. No dma outstanding here (last dma drained at mt=31 barrier).
    f32x4* red4 = (f32x4*)sMem;
    const int wslot = kh * 1024 + quad * 16 + l15;       // + j*64
    const int rslot = (4 * kh) * 64 + quad * 16 + l15;   // + jj*64 + kh'*1024
    f32x4 oacc0[4], oacc1[4];

#define RED_ROUND(RH, OSRC, ODST)                                              \
    __syncthreads();                                                           \
    if (rh == (RH)) {                                                          \
        _Pragma("unroll")                                                      \
        for (int j = 0; j < 16; ++j) red4[wslot + j * 64] = OSRC[j];           \
    }                                                                          \
    __syncthreads();                                                           \
    if (rh == (RH)) {                                                          \
        _Pragma("unroll")                                                      \
        for (int jj = 0; jj < 4; ++jj) {                                       \
            const int base = rslot + jj * 64;                                  \
            ODST[jj] = red4[base] + red4[base + 1024] +                        \
                       red4[base + 2048] + red4[base + 3072];                  \
        }                                                                      \
    }

    RED_ROUND(0, o[0], oacc0)
    RED_ROUND(0, o[1], oacc1)
    RED_ROUND(1, o[0], oacc0)
    RED_ROUND(1, o[1], oacc1)
#undef RED_ROUND

    // ---- epilogue: wave (kh, rh) owns rows [32rh,32rh+32), c [64kh, 64kh+64) ----
    const float* lb = l + ((size_t)b * N_ + row0 + rh * 32) * C_;
    float* ob = out + ((size_t)b * N_ + row0 + rh * 32) * C_;
#pragma unroll
    for (int r = 0; r < 4; ++r) {
        {   // row-tile 0
            const int row = quad * 4 + r;
            const int grow = rh * 32 + row;
            const float inv = 1.f / (sDen[0][grow] + sDen[1][grow] + sDen[2][grow] + sDen[3][grow]);
            const size_t rb = (size_t)row * C_;
#pragma unroll
            for (int jj = 0; jj < 4; ++jj) {
                const int c = kh * 64 + jj * 16 + l15;
                ob[rb + c] = lb[rb + c] + oacc0[jj][r] * inv;
            }
        }
        {   // row-tile 1
            const int row = 16 + quad * 4 + r;
            const int grow = rh * 32 + row;
            const float inv = 1.f / (sDen[0][grow] + sDen[1][grow] + sDen[2][grow] + sDen[3][grow]);
            const size_t rb = (size_t)row * C_;
#pragma unroll
            for (int jj = 0; jj < 4; ++jj) {
                const int c = kh * 64 + jj * 16 + l15;
                ob[rb + c] = lb[rb + c] + oacc1[jj][r] * inv;
            }
        }
    }
}

extern "C" void kernel_launch(void* const* d_in, const int* in_sizes, int n_in,
                              void* d_out, int out_size, void* d_ws, size_t ws_size,
                              hipStream_t stream) {
    (void)in_sizes; (void)n_in; (void)out_size; (void)ws_size;
    const float* l = (const float*)d_in[0];
    const float* g = (const float*)d_in[1];
    float* outp = (float*)d_out;

    char* ws = (char*)d_ws;
    unsigned short* gmc = (unsigned short*)ws;                                   // 4 MB (normalized, [b][m][c])
    unsigned short* gcm = (unsigned short*)(ws + (size_t)B_ * M_ * C_ * 2);      // 4 MB (raw, [b][c][m])

    k_prep<<<dim3(M_ / 64, B_), 1024, 0, stream>>>(g, gcm, gmc);
    k_main<<<dim3(N_ / 64 * B_), 512, 0, stream>>>(l, gcm, gmc, outp);
}